// Round 6
// baseline (208.380 us; speedup 1.0000x reference)
//
#include <hip/hip_runtime.h>
#include <math.h>

// Problem constants
#define B_N 2
#define S_N 2048
#define DM  512
#define H_N 8
#define DH  64
#define NC  32     // number of chunks = S/64
#define CH  64     // chunk length
#define NBLK 512

typedef __bf16 bf16x8 __attribute__((ext_vector_type(8)));
typedef float  f32x4  __attribute__((ext_vector_type(4)));

__device__ __forceinline__ unsigned short f2bf(float f) {
    unsigned int u = __float_as_uint(f);
    u += 0x7FFFu + ((u >> 16) & 1u);          // round-to-nearest-even
    return (unsigned short)(u >> 16);
}

__device__ __forceinline__ void gload16(const void* g, void* l) {
    __builtin_amdgcn_global_load_lds(
        (const __attribute__((address_space(1))) unsigned int*)g,
        (__attribute__((address_space(3))) unsigned int*)l, 16, 0, 0);
}

// Software grid barrier, TREE + CACHELINE-PADDED.
// ROUND-6 FIX: round-5's per-barrier stride (4096 u32) was smaller than the
// region actually used (flags end at 2560+63*32 = 4576 u32), so barrier i's
// flag broadcasts for groups 48..63 landed in barrier i+1's L0 counters ->
// pre-incremented counters -> barrier released one block short -> absmax
// 0.155 fail.  Stride is now 8192 u32 (32KB); intra-barrier offsets are
// unchanged and verified to fit (max 4576 < 8192).
// Layout per barrier i (u32 indices, stride 8192):
//   L0[g]  @ i*8192 + g*32        (g = bid>>3, 0..63)
//   L1[s]  @ i*8192 + 2048 + s*32 (s = g>>3,   0..7)
//   L2     @ i*8192 + 2304
//   flag[g]@ i*8192 + 2560 + g*32 (ends 4576, dead pad to 8192)
__device__ __forceinline__ void gridbar(unsigned int* B, int i) {
    __syncthreads();
    if (threadIdx.x == 0) {
        unsigned int* base = B + i * 8192;
        const unsigned g = blockIdx.x >> 3;                // 0..63
        __threadfence();                                   // release (wbl2)
        if (__hip_atomic_fetch_add(base + g * 32, 1u, __ATOMIC_RELAXED,
                                   __HIP_MEMORY_SCOPE_AGENT) == 7u) {
            if (__hip_atomic_fetch_add(base + 2048 + (g >> 3) * 32, 1u,
                                       __ATOMIC_RELAXED,
                                       __HIP_MEMORY_SCOPE_AGENT) == 7u) {
                if (__hip_atomic_fetch_add(base + 2304, 1u, __ATOMIC_RELAXED,
                                           __HIP_MEMORY_SCOPE_AGENT) == 7u) {
                    #pragma unroll
                    for (int f = 0; f < 64; ++f)
                        __hip_atomic_store(base + 2560 + f * 32, 1u,
                                           __ATOMIC_RELAXED,
                                           __HIP_MEMORY_SCOPE_AGENT);
                }
            }
        }
        while (__hip_atomic_load(base + 2560 + g * 32, __ATOMIC_RELAXED,
                                 __HIP_MEMORY_SCOPE_AGENT) == 0u)
            __builtin_amdgcn_s_sleep(8);
        __threadfence();                                   // acquire (inv), once
    }
    __syncthreads();
}

// ---------------------------------------------------------------------------
// Single fused kernel, 4 phases, 3 grid barriers (scan fused into attention).
// grid = 512 x 256, 2 blocks/CU co-resident (LDS 43008B x2 <= 160K).
// ---------------------------------------------------------------------------
__global__ __launch_bounds__(256, 2) void fused_all(
    const float* __restrict__ x,   const float* __restrict__ Wqk,
    const float* __restrict__ bqk, const float* __restrict__ Wv,
    const float* __restrict__ bv,  const float* __restrict__ Wo,
    const float* __restrict__ bo,  float* __restrict__ out,
    unsigned int* __restrict__ barmem,
    float* __restrict__ Asum, float* __restrict__ zsum,
    unsigned short* __restrict__ xb,  unsigned short* __restrict__ Wqkb,
    unsigned short* __restrict__ Wvb, unsigned short* __restrict__ Wob,
    unsigned short* __restrict__ qb,  unsigned short* __restrict__ kb_,
    unsigned short* __restrict__ vtb, unsigned short* __restrict__ ctxb)
{
    // Unioned LDS: phase1 uses all 43008 B; attn uses 19712 B; out uses 16384 B.
    __shared__ __align__(16) unsigned char SMEM[43008];

    const int tid = threadIdx.x;
    const int bid = blockIdx.x;

    // =======================================================================
    // Phase 0: fp32 -> bf16 conversion of x, Wqk, Wv, Wo.
    // 786432 float4 units over 131072 threads = exactly 6 each.
    // =======================================================================
    {
        const int g0 = bid * 256 + tid;
        #pragma unroll
        for (int it = 0; it < 6; ++it) {
            int gid = g0 + it * 131072;
            const float* src; unsigned short* dst; int off;
            if (gid < 524288)      { src = x;   dst = xb;   off = gid; }
            else if (gid < 655360) { src = Wqk; dst = Wqkb; off = gid - 524288; }
            else if (gid < 720896) { src = Wv;  dst = Wvb;  off = gid - 655360; }
            else                   { src = Wo;  dst = Wob;  off = gid - 720896; }
            float4 v = ((const float4*)src)[off];
            ushort4 r; r.x = f2bf(v.x); r.y = f2bf(v.y); r.z = f2bf(v.z); r.w = f2bf(v.w);
            ((ushort4*)dst)[off] = r;
        }
    }
    gridbar(barmem, 0);

    // =======================================================================
    // Phase 1: fused projection + per-chunk state sums.  768 tiles over 512
    // blocks (tile % 12 < 4 -> q-blocks, >= 4 -> kv head).
    // =======================================================================
    {
        unsigned short* Alds = (unsigned short*)(SMEM);           // 8 KB
        unsigned short* Blds = (unsigned short*)(SMEM + 8192);    // 16 KB
        unsigned short* ktT  = (unsigned short*)(SMEM + 24576);   // 9216 B
        unsigned short* vtT  = (unsigned short*)(SMEM + 33792);   // 9216 B

        const int w = tid >> 6, l = tid & 63;
        const int wm = w >> 1, wn = w & 1;
        const int lane15 = l & 15, quad = l >> 4;
        const int srow = w * 16 + (l >> 2);   // 0..63
        const int skof = (l & 3) << 3;

        for (int tile = bid; tile < 768; tile += NBLK) {
            const int bx = tile % 12;
            const int m0 = (tile / 12) * 64;
            const int isq = (bx < 4);
            const int h = isq ? 0 : (bx - 4);

            f32x4 acc[2][4];
            #pragma unroll
            for (int i = 0; i < 2; i++)
                #pragma unroll
                for (int j = 0; j < 4; j++) acc[i][j] = (f32x4){0.f, 0.f, 0.f, 0.f};

            for (int k0 = 0; k0 < DM; k0 += 64) {
                __syncthreads();
                gload16(&xb[(size_t)(m0 + srow) * DM + k0 + skof],      (char*)Alds + w * 1024);
                gload16(&xb[(size_t)(m0 + srow) * DM + k0 + 32 + skof], (char*)Alds + 4096 + w * 1024);
                if (isq) {
                    gload16(&Wqkb[(size_t)(bx * 128 + srow) * DM + k0 + skof],           (char*)Blds + w * 1024);
                    gload16(&Wqkb[(size_t)(bx * 128 + 64 + srow) * DM + k0 + skof],      (char*)Blds + 4096 + w * 1024);
                    gload16(&Wqkb[(size_t)(bx * 128 + srow) * DM + k0 + 32 + skof],      (char*)Blds + 8192 + w * 1024);
                    gload16(&Wqkb[(size_t)(bx * 128 + 64 + srow) * DM + k0 + 32 + skof], (char*)Blds + 12288 + w * 1024);
                } else {
                    gload16(&Wqkb[(size_t)(512 + h * 64 + srow) * DM + k0 + skof],       (char*)Blds + w * 1024);
                    gload16(&Wvb[(size_t)(h * 64 + srow) * DM + k0 + skof],              (char*)Blds + 4096 + w * 1024);
                    gload16(&Wqkb[(size_t)(512 + h * 64 + srow) * DM + k0 + 32 + skof],  (char*)Blds + 8192 + w * 1024);
                    gload16(&Wvb[(size_t)(h * 64 + srow) * DM + k0 + 32 + skof],         (char*)Blds + 12288 + w * 1024);
                }
                __syncthreads();

                #pragma unroll
                for (int s = 0; s < 2; s++) {
                    bf16x8 af[2], bfr[4];
                    #pragma unroll
                    for (int i = 0; i < 2; i++)
                        af[i] = *(bf16x8*)&Alds[s * 2048 + (wm * 32 + i * 16 + lane15) * 32 + quad * 8];
                    #pragma unroll
                    for (int j = 0; j < 4; j++)
                        bfr[j] = *(bf16x8*)&Blds[s * 4096 + (wn * 64 + j * 16 + lane15) * 32 + quad * 8];
                    #pragma unroll
                    for (int i = 0; i < 2; i++)
                        #pragma unroll
                        for (int j = 0; j < 4; j++)
                            acc[i][j] = __builtin_amdgcn_mfma_f32_16x16x32_bf16(af[i], bfr[j], acc[i][j], 0, 0, 0);
                }
            }

            const int bbu = m0 >> 11;          // batch index (block-uniform)
            const int t0  = m0 & (S_N - 1);    // global t of local row 0
            const int c0  = t0 >> 6;           // chunk index

            if (isq) {
                #pragma unroll
                for (int i = 0; i < 2; i++) {
                    #pragma unroll
                    for (int rg = 0; rg < 4; rg++) {
                        int m = m0 + wm * 32 + i * 16 + quad * 4 + rg;
                        int bb = m >> 11, t = m & (S_N - 1);
                        #pragma unroll
                        for (int j = 0; j < 4; j++) {
                            int n = bx * 128 + wn * 64 + j * 16 + lane15;   // 0..511
                            float val = acc[i][j][rg] + bqk[n];
                            val = (val > 0.f) ? (val + 1.f) : __expf(val);
                            qb[(((size_t)bb * H_N + (n >> 6)) * S_N + t) * DH + (n & 63)] = f2bf(val);
                        }
                    }
                }
            } else {
                // ---- kv epilogue: wn==0 half is k (elu+1), wn==1 half is v ----
                #pragma unroll
                for (int i = 0; i < 2; i++) {
                    #pragma unroll
                    for (int rg = 0; rg < 4; rg++) {
                        int tl = wm * 32 + i * 16 + quad * 4 + rg;   // local row 0..63
                        int t  = t0 + tl;
                        #pragma unroll
                        for (int j = 0; j < 4; j++) {
                            int col = j * 16 + lane15;               // 0..63 within half
                            if (wn == 0) {
                                float val = acc[i][j][rg] + bqk[512 + h * 64 + col];
                                val = (val > 0.f) ? (val + 1.f) : __expf(val);
                                unsigned short us = f2bf(val);
                                kb_[(((size_t)bbu * H_N + h) * S_N + t) * DH + col] = us;
                                ktT[col * 72 + tl] = us;
                            } else {
                                float val = acc[i][j][rg] + bv[h * 64 + col];
                                vtT[col * 72 + tl] = f2bf(val);
                            }
                        }
                    }
                }
                __syncthreads();

                // ---- coalesced copy vT -> vtb global [bh][d][t] ----
                {
                    size_t vbase = (((size_t)bbu * H_N + h) * DH) * S_N + t0;
                    #pragma unroll
                    for (int it = 0; it < 2; it++) {
                        int idx = it * 2048 + tid * 8;
                        int d = idx >> 6, tt = idx & 63;
                        *(bf16x8*)&vtb[vbase + (size_t)d * S_N + tt] = *(bf16x8*)&vtT[d * 72 + tt];
                    }
                }

                // ---- St via MFMA; wave w owns d2 rows 16w..16w+15 ----
                {
                    int blk = ((bbu * H_N + h) * NC) + c0;
                    bf16x8 va[2];
                    #pragma unroll
                    for (int s = 0; s < 2; s++)
                        va[s] = *(bf16x8*)&vtT[(w * 16 + lane15) * 72 + s * 32 + quad * 8];
                    f32x4 sacc[4];
                    #pragma unroll
                    for (int j = 0; j < 4; j++) sacc[j] = (f32x4){0.f, 0.f, 0.f, 0.f};
                    #pragma unroll
                    for (int j = 0; j < 4; j++)
                        #pragma unroll
                        for (int s = 0; s < 2; s++) {
                            bf16x8 kB = *(bf16x8*)&ktT[(j * 16 + lane15) * 72 + s * 32 + quad * 8];
                            sacc[j] = __builtin_amdgcn_mfma_f32_16x16x32_bf16(va[s], kB, sacc[j], 0, 0, 0);
                        }
                    #pragma unroll
                    for (int j = 0; j < 4; j++)
                        #pragma unroll
                        for (int rg = 0; rg < 4; rg++)
                            Asum[(size_t)blk * 4096 + (w * 16 + quad * 4 + rg) * 64 + j * 16 + lane15] = sacc[j][rg];
                }

                // ---- z: threads 0..63, one d1 each ----
                if (tid < 64) {
                    float z = 0.f;
                    #pragma unroll
                    for (int p = 0; p < 8; p++) {
                        bf16x8 kk = *(bf16x8*)&ktT[tid * 72 + p * 8];
                        #pragma unroll
                        for (int e = 0; e < 8; e++) z += (float)kk[e];
                    }
                    zsum[(size_t)((bbu * H_N + h) * NC + c0) * 64 + tid] = z;
                }
            }
        }
    }
    gridbar(barmem, 1);

    // =======================================================================
    // Phase 2: per-chunk attention with FUSED exclusive prefix scan.
    // Block (bh,c) computes its own Spt/zpref prefix over chunks 0..c-1 from
    // raw Asum/zsum (same f32 summation order as the old scan kernel ->
    // bit-identical values), staged into LDS.  1:1 block -> (bh, chunk).
    // =======================================================================
    {
        unsigned short* P    = (unsigned short*)(SMEM);           // 9216 B
        float* nupart        = (float*)(SMEM + 9216);             // 1024 B
        unsigned short* SptL = (unsigned short*)(SMEM + 10240);   // 9216 B
        float* zprefL        = (float*)(SMEM + 19456);            // 256 B

        const int blk = bid;                  // 0..511
        const int bh = blk >> 5, c = blk & 31;
        const int b = bh >> 3, h = bh & 7;
        const int w = tid >> 6, l = tid & 63;
        const int lane15 = l & 15, quad = l >> 4;

        const unsigned short* qc  = qb  + (size_t)bh * S_N * DH + c * CH * DH;  // [t][d]
        const unsigned short* kc  = kb_ + (size_t)bh * S_N * DH + c * CH * DH;  // [u][d]
        const unsigned short* vtc = vtb + (size_t)bh * DH * S_N + c * CH;       // [d2][t], stride S_N

        bf16x8 af[2];
        #pragma unroll
        for (int s = 0; s < 2; s++)
            af[s] = *(const bf16x8*)&qc[(w * 16 + lane15) * DH + s * 32 + quad * 8];

        // ---- in-block exclusive prefix: Spt (f32 sums -> bf16 LDS), zpref ----
        {
            const int d2 = tid >> 2, d1b = (tid & 3) << 4;    // 16 d1 per thread
            float sp[16];
            #pragma unroll
            for (int i = 0; i < 16; i++) sp[i] = 0.f;
            const float* abase = Asum + (size_t)bh * NC * 4096 + d2 * 64 + d1b;
            for (int cc = 0; cc < c; ++cc) {
                const float4* a4 = (const float4*)(abase + (size_t)cc * 4096);
                #pragma unroll
                for (int q4 = 0; q4 < 4; ++q4) {
                    float4 v = a4[q4];
                    sp[q4 * 4 + 0] += v.x; sp[q4 * 4 + 1] += v.y;
                    sp[q4 * 4 + 2] += v.z; sp[q4 * 4 + 3] += v.w;
                }
            }
            #pragma unroll
            for (int i = 0; i < 16; i++)
                SptL[d2 * 72 + d1b + i] = f2bf(sp[i]);
            if (tid < 64) {
                float z = 0.f;
                const float* zbase = zsum + (size_t)bh * NC * 64 + tid;
                for (int cc = 0; cc < c; ++cc) z += zbase[cc * 64];
                zprefL[tid] = z;
            }
        }

        // scores S[t][u]
        f32x4 sacc[4];
        #pragma unroll
        for (int j = 0; j < 4; j++) sacc[j] = (f32x4){0.f, 0.f, 0.f, 0.f};
        #pragma unroll
        for (int j = 0; j < 4; j++)
            #pragma unroll
            for (int s = 0; s < 2; s++) {
                bf16x8 bk = *(const bf16x8*)&kc[(j * 16 + lane15) * DH + s * 32 + quad * 8];
                sacc[j] = __builtin_amdgcn_mfma_f32_16x16x32_bf16(af[s], bk, sacc[j], 0, 0, 0);
            }

        // causal mask + store P (bf16) to LDS
        const int r0 = w * 16 + quad * 4;
        #pragma unroll
        for (int j = 0; j < 4; j++) {
            int u = j * 16 + lane15;
            #pragma unroll
            for (int rg = 0; rg < 4; rg++) {
                int rr = r0 + rg;
                float v = (u <= rr) ? sacc[j][rg] : 0.f;
                P[rr * 72 + u] = f2bf(v);
            }
        }
        __syncthreads();   // covers P, SptL, zprefL

        // nu: thread (tl, part) sums P[tl][16*part..+15] + q.zpref strip
        const int tl = tid >> 2, part = tid & 3;
        float nup = 0.f;
        {
            bf16x8 p0 = *(const bf16x8*)&P[tl * 72 + part * 16];
            bf16x8 p1 = *(const bf16x8*)&P[tl * 72 + part * 16 + 8];
            bf16x8 q0 = *(const bf16x8*)&qc[tl * DH + part * 16];
            bf16x8 q1 = *(const bf16x8*)&qc[tl * DH + part * 16 + 8];
            #pragma unroll
            for (int i = 0; i < 8; i++) {
                nup += (float)p0[i] + (float)p1[i];
                nup += (float)q0[i] * zprefL[part * 16 + i];
                nup += (float)q1[i] * zprefL[part * 16 + 8 + i];
            }
        }
        nupart[(tl << 2) + part] = nup;
        __syncthreads();

        // numerator: intra (P @ vt) + inter (q @ Spt), fused accumulator
        bf16x8 pa[2];
        #pragma unroll
        for (int s = 0; s < 2; s++)
            pa[s] = *(const bf16x8*)&P[(w * 16 + lane15) * 72 + s * 32 + quad * 8];

        f32x4 acc[4];
        #pragma unroll
        for (int j = 0; j < 4; j++) acc[j] = (f32x4){0.f, 0.f, 0.f, 0.f};
        #pragma unroll
        for (int j = 0; j < 4; j++)
            #pragma unroll
            for (int s = 0; s < 2; s++) {
                bf16x8 bv8 = *(const bf16x8*)&vtc[(size_t)(j * 16 + lane15) * S_N + s * 32 + quad * 8];
                bf16x8 bs  = *(const bf16x8*)&SptL[(j * 16 + lane15) * 72 + s * 32 + quad * 8];
                acc[j] = __builtin_amdgcn_mfma_f32_16x16x32_bf16(pa[s], bv8, acc[j], 0, 0, 0);
                acc[j] = __builtin_amdgcn_mfma_f32_16x16x32_bf16(af[s], bs, acc[j], 0, 0, 0);
            }

        // epilogue: divide by nu, write ctx bf16 [b*S+t][DM]
        #pragma unroll
        for (int rg = 0; rg < 4; rg++) {
            int rr = r0 + rg;
            float nu = nupart[(rr << 2) + 0] + nupart[(rr << 2) + 1]
                     + nupart[(rr << 2) + 2] + nupart[(rr << 2) + 3];
            float inv = 1.f / nu;
            size_t obase = ((size_t)b * S_N + c * CH + rr) * DM + h * DH;
            #pragma unroll
            for (int j = 0; j < 4; j++)
                ctxb[obase + j * 16 + lane15] = f2bf(acc[j][rg] * inv);
        }
    }
    gridbar(barmem, 2);

    // =======================================================================
    // Phase 3: output projection via bf16 MFMA.  1:1 block -> 64x64 tile.
    // =======================================================================
    {
        unsigned short* Alds = (unsigned short*)(SMEM);          // 8 KB
        unsigned short* Blds = (unsigned short*)(SMEM + 8192);   // 8 KB

        const int w = tid >> 6, l = tid & 63;
        const int wm = w >> 1, wn = w & 1;
        const int lane15 = l & 15, quad = l >> 4;
        const int n0 = (bid & 7) * 64;
        const int m0 = (bid >> 3) * 64;

        const int srow = w * 16 + (l >> 2);
        const int skof = (l & 3) << 3;

        f32x4 acc[2][2];
        #pragma unroll
        for (int i = 0; i < 2; i++)
            #pragma unroll
            for (int j = 0; j < 2; j++) acc[i][j] = (f32x4){0.f, 0.f, 0.f, 0.f};

        for (int k0 = 0; k0 < DM; k0 += 64) {
            __syncthreads();
            gload16(&ctxb[(size_t)(m0 + srow) * DM + k0 + skof],      (char*)Alds + w * 1024);
            gload16(&ctxb[(size_t)(m0 + srow) * DM + k0 + 32 + skof], (char*)Alds + 4096 + w * 1024);
            gload16(&Wob[(size_t)(n0 + srow) * DM + k0 + skof],       (char*)Blds + w * 1024);
            gload16(&Wob[(size_t)(n0 + srow) * DM + k0 + 32 + skof],  (char*)Blds + 4096 + w * 1024);
            __syncthreads();

            #pragma unroll
            for (int s = 0; s < 2; s++) {
                bf16x8 af2[2], bfr[2];
                #pragma unroll
                for (int i = 0; i < 2; i++)
                    af2[i] = *(bf16x8*)&Alds[s * 2048 + (wm * 32 + i * 16 + lane15) * 32 + quad * 8];
                #pragma unroll
                for (int j = 0; j < 2; j++)
                    bfr[j] = *(bf16x8*)&Blds[s * 2048 + (wn * 32 + j * 16 + lane15) * 32 + quad * 8];
                #pragma unroll
                for (int i = 0; i < 2; i++)
                    #pragma unroll
                    for (int j = 0; j < 2; j++)
                        acc[i][j] = __builtin_amdgcn_mfma_f32_16x16x32_bf16(af2[i], bfr[j], acc[i][j], 0, 0, 0);
            }
        }

        #pragma unroll
        for (int i = 0; i < 2; i++) {
            #pragma unroll
            for (int rg = 0; rg < 4; rg++) {
                int m = m0 + wm * 32 + i * 16 + quad * 4 + rg;
                #pragma unroll
                for (int j = 0; j < 2; j++) {
                    int n = n0 + wn * 32 + j * 16 + lane15;
                    out[(size_t)m * DM + n] = acc[i][j][rg] + bo[n];
                }
            }
        }
    }
}

// ---------------------------------------------------------------------------
extern "C" void kernel_launch(void* const* d_in, const int* in_sizes, int n_in,
                              void* d_out, int out_size, void* d_ws, size_t ws_size,
                              hipStream_t stream)
{
    const float* x   = (const float*)d_in[0];
    const float* Wqk = (const float*)d_in[1];
    const float* bqk = (const float*)d_in[2];
    const float* Wv  = (const float*)d_in[3];
    const float* bv  = (const float*)d_in[4];
    const float* Wo  = (const float*)d_in[5];
    const float* bo  = (const float*)d_in[6];
    float* out = (float*)d_out;

    const size_t NTOK = (size_t)B_N * S_N * DM;   // 2,097,152
    unsigned int* barmem = (unsigned int*)d_ws;   // 3 barriers x 32KB stride
    float* Asum = (float*)d_ws + 24576;           // past barrier region (96KB)
    float* zsum = Asum + NTOK;                    // 32768 fp32
    unsigned short* xb   = (unsigned short*)(zsum + 32768);
    unsigned short* Wqkb = xb   + NTOK;
    unsigned short* Wvb  = Wqkb + 524288;
    unsigned short* Wob  = Wvb  + 262144;
    unsigned short* qb   = Wob  + 262144;
    unsigned short* kb_  = qb   + NTOK;
    unsigned short* vtb  = kb_  + NTOK;
    unsigned short* ctxb = vtb  + NTOK;

    hipMemsetAsync(barmem, 0, 98304, stream);
    fused_all<<<dim3(NBLK), dim3(256), 0, stream>>>(
        x, Wqk, bqk, Wv, bv, Wo, bo, out, barmem,
        Asum, zsum, xb, Wqkb, Wvb, Wob, qb, kb_, vtb, ctxb);
}

// Round 7
// 143.421 us; speedup vs baseline: 1.4529x; 1.4529x over previous
//
#include <hip/hip_runtime.h>
#include <math.h>

// Problem constants
#define B_N 2
#define S_N 2048
#define DM  512
#define H_N 8
#define DH  64
#define NC  32     // number of chunks = S/64
#define CH  64     // chunk length
#define NBLK 512

typedef __bf16 bf16x8 __attribute__((ext_vector_type(8)));
typedef float  f32x4  __attribute__((ext_vector_type(4)));
typedef unsigned int u32x2 __attribute__((ext_vector_type(2)));
typedef unsigned int u32x4 __attribute__((ext_vector_type(4)));

__device__ __forceinline__ unsigned short f2bf(float f) {
    unsigned int u = __float_as_uint(f);
    u += 0x7FFFu + ((u >> 16) & 1u);          // round-to-nearest-even
    return (unsigned short)(u >> 16);
}

__device__ __forceinline__ void gload16(const void* g, void* l) {
    __builtin_amdgcn_global_load_lds(
        (const __attribute__((address_space(1))) unsigned int*)g,
        (__attribute__((address_space(3))) unsigned int*)l, 16, 0, 0);
}

// ---------------------------------------------------------------------------
// Write-through (agent-coherent) stores: sc1 makes the store visible at the
// coherence point with NO wbl2 fence.  In-session proof: the barrier's flag
// broadcast (__hip_atomic_store AGENT = global_store sc1) has been observed
// across XCDs by relaxed loads in rounds 3-6 with no intervening fence.
// All cross-phase buffers are written in exactly one phase and never read
// before it (audited), and kernel-dispatch acquire handles cross-iteration
// cache invalidation (the 5-kernel baseline relied on exactly that), so
// consumers can use plain cached loads: no buffer_inv needed either.
// ---------------------------------------------------------------------------
__device__ __forceinline__ void st_wt16(void* p, unsigned v) {
    asm volatile("global_store_short %0, %1, off sc1" :: "v"(p), "v"(v) : "memory");
}
__device__ __forceinline__ void st_wt32(void* p, unsigned v) {
    asm volatile("global_store_dword %0, %1, off sc1" :: "v"(p), "v"(v) : "memory");
}
__device__ __forceinline__ void st_wt64(void* p, u32x2 v) {
    asm volatile("global_store_dwordx2 %0, %1, off sc1" :: "v"(p), "v"(v) : "memory");
}
__device__ __forceinline__ void st_wt128(void* p, u32x4 v) {
    asm volatile("global_store_dwordx4 %0, %1, off sc1" :: "v"(p), "v"(v) : "memory");
}

// Software grid barrier, TREE, NO CACHE-MAINTENANCE FENCES (round-7 fix).
// Rounds 4/6 proved arrival topology/layout is not the ~40us/barrier cost
// (padded tree == packed tree).  The remaining per-block cost was the
// __threadfence() pair (buffer_wbl2 + buffer_inv serializing ~64x at each
// XCD's L2 controller).  With all cross-phase stores write-through sc1
// (visible once vmcnt(0) drains -- which __syncthreads already emits) and
// consumers reading only never-before-cached lines, both fences are deleted.
// Layout per barrier i (u32 indices, stride 8192 = 32KB):
//   L0[g]  @ i*8192 + g*32        (g = bid>>3, 0..63)
//   L1[s]  @ i*8192 + 2048 + s*32 (s = g>>3,   0..7)
//   L2     @ i*8192 + 2304
//   flag[g]@ i*8192 + 2560 + g*32 (ends 4576, dead pad to 8192)
__device__ __forceinline__ void gridbar(unsigned int* B, int i) {
    __syncthreads();   // compiler emits s_waitcnt vmcnt(0) -> sc1 stores visible
    if (threadIdx.x == 0) {
        unsigned int* base = B + i * 8192;
        const unsigned g = blockIdx.x >> 3;                // 0..63
        if (__hip_atomic_fetch_add(base + g * 32, 1u, __ATOMIC_RELAXED,
                                   __HIP_MEMORY_SCOPE_AGENT) == 7u) {
            if (__hip_atomic_fetch_add(base + 2048 + (g >> 3) * 32, 1u,
                                       __ATOMIC_RELAXED,
                                       __HIP_MEMORY_SCOPE_AGENT) == 7u) {
                if (__hip_atomic_fetch_add(base + 2304, 1u, __ATOMIC_RELAXED,
                                           __HIP_MEMORY_SCOPE_AGENT) == 7u) {
                    #pragma unroll
                    for (int f = 0; f < 64; ++f)
                        __hip_atomic_store(base + 2560 + f * 32, 1u,
                                           __ATOMIC_RELAXED,
                                           __HIP_MEMORY_SCOPE_AGENT);
                }
            }
        }
        while (__hip_atomic_load(base + 2560 + g * 32, __ATOMIC_RELAXED,
                                 __HIP_MEMORY_SCOPE_AGENT) == 0u)
            __builtin_amdgcn_s_sleep(8);
        asm volatile("" ::: "memory");   // compiler fence: no load hoisting
    }
    __syncthreads();
}

// ---------------------------------------------------------------------------
// Single fused kernel, 4 phases, 3 grid barriers (scan fused into attention).
// grid = 512 x 256, 2 blocks/CU co-resident (LDS 43008B x2 <= 160K).
// ---------------------------------------------------------------------------
__global__ __launch_bounds__(256, 2) void fused_all(
    const float* __restrict__ x,   const float* __restrict__ Wqk,
    const float* __restrict__ bqk, const float* __restrict__ Wv,
    const float* __restrict__ bv,  const float* __restrict__ Wo,
    const float* __restrict__ bo,  float* __restrict__ out,
    unsigned int* __restrict__ barmem,
    float* __restrict__ Asum, float* __restrict__ zsum,
    unsigned short* __restrict__ xb,  unsigned short* __restrict__ Wqkb,
    unsigned short* __restrict__ Wvb, unsigned short* __restrict__ Wob,
    unsigned short* __restrict__ qb,  unsigned short* __restrict__ kb_,
    unsigned short* __restrict__ vtb, unsigned short* __restrict__ ctxb)
{
    // Unioned LDS: phase1 uses all 43008 B; attn uses 19712 B; out uses 16384 B.
    __shared__ __align__(16) unsigned char SMEM[43008];

    const int tid = threadIdx.x;
    const int bid = blockIdx.x;

    // =======================================================================
    // Phase 0: fp32 -> bf16 conversion of x, Wqk, Wv, Wo.
    // 786432 float4 units over 131072 threads = exactly 6 each.
    // =======================================================================
    {
        const int g0 = bid * 256 + tid;
        #pragma unroll
        for (int it = 0; it < 6; ++it) {
            int gid = g0 + it * 131072;
            const float* src; unsigned short* dst; int off;
            if (gid < 524288)      { src = x;   dst = xb;   off = gid; }
            else if (gid < 655360) { src = Wqk; dst = Wqkb; off = gid - 524288; }
            else if (gid < 720896) { src = Wv;  dst = Wvb;  off = gid - 655360; }
            else                   { src = Wo;  dst = Wob;  off = gid - 720896; }
            float4 v = ((const float4*)src)[off];
            ushort4 r; r.x = f2bf(v.x); r.y = f2bf(v.y); r.z = f2bf(v.z); r.w = f2bf(v.w);
            st_wt64(&((ushort4*)dst)[off], __builtin_bit_cast(u32x2, r));
        }
    }
    gridbar(barmem, 0);

    // =======================================================================
    // Phase 1: fused projection + per-chunk state sums.  768 tiles over 512
    // blocks (tile % 12 < 4 -> q-blocks, >= 4 -> kv head).
    // =======================================================================
    {
        unsigned short* Alds = (unsigned short*)(SMEM);           // 8 KB
        unsigned short* Blds = (unsigned short*)(SMEM + 8192);    // 16 KB
        unsigned short* ktT  = (unsigned short*)(SMEM + 24576);   // 9216 B
        unsigned short* vtT  = (unsigned short*)(SMEM + 33792);   // 9216 B

        const int w = tid >> 6, l = tid & 63;
        const int wm = w >> 1, wn = w & 1;
        const int lane15 = l & 15, quad = l >> 4;
        const int srow = w * 16 + (l >> 2);   // 0..63
        const int skof = (l & 3) << 3;

        for (int tile = bid; tile < 768; tile += NBLK) {
            const int bx = tile % 12;
            const int m0 = (tile / 12) * 64;
            const int isq = (bx < 4);
            const int h = isq ? 0 : (bx - 4);

            f32x4 acc[2][4];
            #pragma unroll
            for (int i = 0; i < 2; i++)
                #pragma unroll
                for (int j = 0; j < 4; j++) acc[i][j] = (f32x4){0.f, 0.f, 0.f, 0.f};

            for (int k0 = 0; k0 < DM; k0 += 64) {
                __syncthreads();
                gload16(&xb[(size_t)(m0 + srow) * DM + k0 + skof],      (char*)Alds + w * 1024);
                gload16(&xb[(size_t)(m0 + srow) * DM + k0 + 32 + skof], (char*)Alds + 4096 + w * 1024);
                if (isq) {
                    gload16(&Wqkb[(size_t)(bx * 128 + srow) * DM + k0 + skof],           (char*)Blds + w * 1024);
                    gload16(&Wqkb[(size_t)(bx * 128 + 64 + srow) * DM + k0 + skof],      (char*)Blds + 4096 + w * 1024);
                    gload16(&Wqkb[(size_t)(bx * 128 + srow) * DM + k0 + 32 + skof],      (char*)Blds + 8192 + w * 1024);
                    gload16(&Wqkb[(size_t)(bx * 128 + 64 + srow) * DM + k0 + 32 + skof], (char*)Blds + 12288 + w * 1024);
                } else {
                    gload16(&Wqkb[(size_t)(512 + h * 64 + srow) * DM + k0 + skof],       (char*)Blds + w * 1024);
                    gload16(&Wvb[(size_t)(h * 64 + srow) * DM + k0 + skof],              (char*)Blds + 4096 + w * 1024);
                    gload16(&Wqkb[(size_t)(512 + h * 64 + srow) * DM + k0 + 32 + skof],  (char*)Blds + 8192 + w * 1024);
                    gload16(&Wvb[(size_t)(h * 64 + srow) * DM + k0 + 32 + skof],         (char*)Blds + 12288 + w * 1024);
                }
                __syncthreads();

                #pragma unroll
                for (int s = 0; s < 2; s++) {
                    bf16x8 af[2], bfr[4];
                    #pragma unroll
                    for (int i = 0; i < 2; i++)
                        af[i] = *(bf16x8*)&Alds[s * 2048 + (wm * 32 + i * 16 + lane15) * 32 + quad * 8];
                    #pragma unroll
                    for (int j = 0; j < 4; j++)
                        bfr[j] = *(bf16x8*)&Blds[s * 4096 + (wn * 64 + j * 16 + lane15) * 32 + quad * 8];
                    #pragma unroll
                    for (int i = 0; i < 2; i++)
                        #pragma unroll
                        for (int j = 0; j < 4; j++)
                            acc[i][j] = __builtin_amdgcn_mfma_f32_16x16x32_bf16(af[i], bfr[j], acc[i][j], 0, 0, 0);
                }
            }

            const int bbu = m0 >> 11;          // batch index (block-uniform)
            const int t0  = m0 & (S_N - 1);    // global t of local row 0
            const int c0  = t0 >> 6;           // chunk index

            if (isq) {
                #pragma unroll
                for (int i = 0; i < 2; i++) {
                    #pragma unroll
                    for (int rg = 0; rg < 4; rg++) {
                        int m = m0 + wm * 32 + i * 16 + quad * 4 + rg;
                        int bb = m >> 11, t = m & (S_N - 1);
                        #pragma unroll
                        for (int j = 0; j < 4; j++) {
                            int n = bx * 128 + wn * 64 + j * 16 + lane15;   // 0..511
                            float val = acc[i][j][rg] + bqk[n];
                            val = (val > 0.f) ? (val + 1.f) : __expf(val);
                            st_wt16(&qb[(((size_t)bb * H_N + (n >> 6)) * S_N + t) * DH + (n & 63)],
                                    (unsigned)f2bf(val));
                        }
                    }
                }
            } else {
                // ---- kv epilogue: wn==0 half is k (elu+1), wn==1 half is v ----
                #pragma unroll
                for (int i = 0; i < 2; i++) {
                    #pragma unroll
                    for (int rg = 0; rg < 4; rg++) {
                        int tl = wm * 32 + i * 16 + quad * 4 + rg;   // local row 0..63
                        int t  = t0 + tl;
                        #pragma unroll
                        for (int j = 0; j < 4; j++) {
                            int col = j * 16 + lane15;               // 0..63 within half
                            if (wn == 0) {
                                float val = acc[i][j][rg] + bqk[512 + h * 64 + col];
                                val = (val > 0.f) ? (val + 1.f) : __expf(val);
                                unsigned short us = f2bf(val);
                                st_wt16(&kb_[(((size_t)bbu * H_N + h) * S_N + t) * DH + col],
                                        (unsigned)us);
                                ktT[col * 72 + tl] = us;
                            } else {
                                float val = acc[i][j][rg] + bv[h * 64 + col];
                                vtT[col * 72 + tl] = f2bf(val);
                            }
                        }
                    }
                }
                __syncthreads();

                // ---- coalesced copy vT -> vtb global [bh][d][t] ----
                {
                    size_t vbase = (((size_t)bbu * H_N + h) * DH) * S_N + t0;
                    #pragma unroll
                    for (int it = 0; it < 2; it++) {
                        int idx = it * 2048 + tid * 8;
                        int d = idx >> 6, tt = idx & 63;
                        bf16x8 vv = *(bf16x8*)&vtT[d * 72 + tt];
                        st_wt128(&vtb[vbase + (size_t)d * S_N + tt],
                                 __builtin_bit_cast(u32x4, vv));
                    }
                }

                // ---- St via MFMA; wave w owns d2 rows 16w..16w+15 ----
                {
                    int blk = ((bbu * H_N + h) * NC) + c0;
                    bf16x8 va[2];
                    #pragma unroll
                    for (int s = 0; s < 2; s++)
                        va[s] = *(bf16x8*)&vtT[(w * 16 + lane15) * 72 + s * 32 + quad * 8];
                    f32x4 sacc[4];
                    #pragma unroll
                    for (int j = 0; j < 4; j++) sacc[j] = (f32x4){0.f, 0.f, 0.f, 0.f};
                    #pragma unroll
                    for (int j = 0; j < 4; j++)
                        #pragma unroll
                        for (int s = 0; s < 2; s++) {
                            bf16x8 kB = *(bf16x8*)&ktT[(j * 16 + lane15) * 72 + s * 32 + quad * 8];
                            sacc[j] = __builtin_amdgcn_mfma_f32_16x16x32_bf16(va[s], kB, sacc[j], 0, 0, 0);
                        }
                    #pragma unroll
                    for (int j = 0; j < 4; j++)
                        #pragma unroll
                        for (int rg = 0; rg < 4; rg++)
                            st_wt32(&Asum[(size_t)blk * 4096 + (w * 16 + quad * 4 + rg) * 64 + j * 16 + lane15],
                                    __float_as_uint(sacc[j][rg]));
                }

                // ---- z: threads 0..63, one d1 each ----
                if (tid < 64) {
                    float z = 0.f;
                    #pragma unroll
                    for (int p = 0; p < 8; p++) {
                        bf16x8 kk = *(bf16x8*)&ktT[tid * 72 + p * 8];
                        #pragma unroll
                        for (int e = 0; e < 8; e++) z += (float)kk[e];
                    }
                    st_wt32(&zsum[(size_t)((bbu * H_N + h) * NC + c0) * 64 + tid],
                            __float_as_uint(z));
                }
            }
        }
    }
    gridbar(barmem, 1);

    // =======================================================================
    // Phase 2: per-chunk attention with FUSED exclusive prefix scan.
    // Block (bh,c) computes its own Spt/zpref prefix over chunks 0..c-1 from
    // raw Asum/zsum (same f32 summation order as the old scan kernel ->
    // bit-identical values), staged into LDS.  1:1 block -> (bh, chunk).
    // =======================================================================
    {
        unsigned short* P    = (unsigned short*)(SMEM);           // 9216 B
        float* nupart        = (float*)(SMEM + 9216);             // 1024 B
        unsigned short* SptL = (unsigned short*)(SMEM + 10240);   // 9216 B
        float* zprefL        = (float*)(SMEM + 19456);            // 256 B

        const int blk = bid;                  // 0..511
        const int bh = blk >> 5, c = blk & 31;
        const int b = bh >> 3, h = bh & 7;
        const int w = tid >> 6, l = tid & 63;
        const int lane15 = l & 15, quad = l >> 4;

        const unsigned short* qc  = qb  + (size_t)bh * S_N * DH + c * CH * DH;  // [t][d]
        const unsigned short* kc  = kb_ + (size_t)bh * S_N * DH + c * CH * DH;  // [u][d]
        const unsigned short* vtc = vtb + (size_t)bh * DH * S_N + c * CH;       // [d2][t], stride S_N

        bf16x8 af[2];
        #pragma unroll
        for (int s = 0; s < 2; s++)
            af[s] = *(const bf16x8*)&qc[(w * 16 + lane15) * DH + s * 32 + quad * 8];

        // ---- in-block exclusive prefix: Spt (f32 sums -> bf16 LDS), zpref ----
        {
            const int d2 = tid >> 2, d1b = (tid & 3) << 4;    // 16 d1 per thread
            float sp[16];
            #pragma unroll
            for (int i = 0; i < 16; i++) sp[i] = 0.f;
            const float* abase = Asum + (size_t)bh * NC * 4096 + d2 * 64 + d1b;
            for (int cc = 0; cc < c; ++cc) {
                const float4* a4 = (const float4*)(abase + (size_t)cc * 4096);
                #pragma unroll
                for (int q4 = 0; q4 < 4; ++q4) {
                    float4 v = a4[q4];
                    sp[q4 * 4 + 0] += v.x; sp[q4 * 4 + 1] += v.y;
                    sp[q4 * 4 + 2] += v.z; sp[q4 * 4 + 3] += v.w;
                }
            }
            #pragma unroll
            for (int i = 0; i < 16; i++)
                SptL[d2 * 72 + d1b + i] = f2bf(sp[i]);
            if (tid < 64) {
                float z = 0.f;
                const float* zbase = zsum + (size_t)bh * NC * 64 + tid;
                for (int cc = 0; cc < c; ++cc) z += zbase[cc * 64];
                zprefL[tid] = z;
            }
        }

        // scores S[t][u]
        f32x4 sacc[4];
        #pragma unroll
        for (int j = 0; j < 4; j++) sacc[j] = (f32x4){0.f, 0.f, 0.f, 0.f};
        #pragma unroll
        for (int j = 0; j < 4; j++)
            #pragma unroll
            for (int s = 0; s < 2; s++) {
                bf16x8 bk = *(const bf16x8*)&kc[(j * 16 + lane15) * DH + s * 32 + quad * 8];
                sacc[j] = __builtin_amdgcn_mfma_f32_16x16x32_bf16(af[s], bk, sacc[j], 0, 0, 0);
            }

        // causal mask + store P (bf16) to LDS
        const int r0 = w * 16 + quad * 4;
        #pragma unroll
        for (int j = 0; j < 4; j++) {
            int u = j * 16 + lane15;
            #pragma unroll
            for (int rg = 0; rg < 4; rg++) {
                int rr = r0 + rg;
                float v = (u <= rr) ? sacc[j][rg] : 0.f;
                P[rr * 72 + u] = f2bf(v);
            }
        }
        __syncthreads();   // covers P, SptL, zprefL

        // nu: thread (tl, part) sums P[tl][16*part..+15] + q.zpref strip
        const int tl = tid >> 2, part = tid & 3;
        float nup = 0.f;
        {
            bf16x8 p0 = *(const bf16x8*)&P[tl * 72 + part * 16];
            bf16x8 p1 = *(const bf16x8*)&P[tl * 72 + part * 16 + 8];
            bf16x8 q0 = *(const bf16x8*)&qc[tl * DH + part * 16];
            bf16x8 q1 = *(const bf16x8*)&qc[tl * DH + part * 16 + 8];
            #pragma unroll
            for (int i = 0; i < 8; i++) {
                nup += (float)p0[i] + (float)p1[i];
                nup += (float)q0[i] * zprefL[part * 16 + i];
                nup += (float)q1[i] * zprefL[part * 16 + 8 + i];
            }
        }
        nupart[(tl << 2) + part] = nup;
        __syncthreads();

        // numerator: intra (P @ vt) + inter (q @ Spt), fused accumulator
        bf16x8 pa[2];
        #pragma unroll
        for (int s = 0; s < 2; s++)
            pa[s] = *(const bf16x8*)&P[(w * 16 + lane15) * 72 + s * 32 + quad * 8];

        f32x4 acc[4];
        #pragma unroll
        for (int j = 0; j < 4; j++) acc[j] = (f32x4){0.f, 0.f, 0.f, 0.f};
        #pragma unroll
        for (int j = 0; j < 4; j++)
            #pragma unroll
            for (int s = 0; s < 2; s++) {
                bf16x8 bv8 = *(const bf16x8*)&vtc[(size_t)(j * 16 + lane15) * S_N + s * 32 + quad * 8];
                bf16x8 bs  = *(const bf16x8*)&SptL[(j * 16 + lane15) * 72 + s * 32 + quad * 8];
                acc[j] = __builtin_amdgcn_mfma_f32_16x16x32_bf16(pa[s], bv8, acc[j], 0, 0, 0);
                acc[j] = __builtin_amdgcn_mfma_f32_16x16x32_bf16(af[s], bs, acc[j], 0, 0, 0);
            }

        // epilogue: divide by nu, write ctx bf16 [b*S+t][DM]
        #pragma unroll
        for (int rg = 0; rg < 4; rg++) {
            int rr = r0 + rg;
            float nu = nupart[(rr << 2) + 0] + nupart[(rr << 2) + 1]
                     + nupart[(rr << 2) + 2] + nupart[(rr << 2) + 3];
            float inv = 1.f / nu;
            size_t obase = ((size_t)b * S_N + c * CH + rr) * DM + h * DH;
            #pragma unroll
            for (int j = 0; j < 4; j++)
                st_wt16(&ctxb[obase + j * 16 + lane15],
                        (unsigned)f2bf(acc[j][rg] * inv));
        }
    }
    gridbar(barmem, 2);

    // =======================================================================
    // Phase 3: output projection via bf16 MFMA.  1:1 block -> 64x64 tile.
    // =======================================================================
    {
        unsigned short* Alds = (unsigned short*)(SMEM);          // 8 KB
        unsigned short* Blds = (unsigned short*)(SMEM + 8192);   // 8 KB

        const int w = tid >> 6, l = tid & 63;
        const int wm = w >> 1, wn = w & 1;
        const int lane15 = l & 15, quad = l >> 4;
        const int n0 = (bid & 7) * 64;
        const int m0 = (bid >> 3) * 64;

        const int srow = w * 16 + (l >> 2);
        const int skof = (l & 3) << 3;

        f32x4 acc[2][2];
        #pragma unroll
        for (int i = 0; i < 2; i++)
            #pragma unroll
            for (int j = 0; j < 2; j++) acc[i][j] = (f32x4){0.f, 0.f, 0.f, 0.f};

        for (int k0 = 0; k0 < DM; k0 += 64) {
            __syncthreads();
            gload16(&ctxb[(size_t)(m0 + srow) * DM + k0 + skof],      (char*)Alds + w * 1024);
            gload16(&ctxb[(size_t)(m0 + srow) * DM + k0 + 32 + skof], (char*)Alds + 4096 + w * 1024);
            gload16(&Wob[(size_t)(n0 + srow) * DM + k0 + skof],       (char*)Blds + w * 1024);
            gload16(&Wob[(size_t)(n0 + srow) * DM + k0 + 32 + skof],  (char*)Blds + 4096 + w * 1024);
            __syncthreads();

            #pragma unroll
            for (int s = 0; s < 2; s++) {
                bf16x8 af2[2], bfr[2];
                #pragma unroll
                for (int i = 0; i < 2; i++)
                    af2[i] = *(bf16x8*)&Alds[s * 2048 + (wm * 32 + i * 16 + lane15) * 32 + quad * 8];
                #pragma unroll
                for (int j = 0; j < 2; j++)
                    bfr[j] = *(bf16x8*)&Blds[s * 2048 + (wn * 32 + j * 16 + lane15) * 32 + quad * 8];
                #pragma unroll
                for (int i = 0; i < 2; i++)
                    #pragma unroll
                    for (int j = 0; j < 2; j++)
                        acc[i][j] = __builtin_amdgcn_mfma_f32_16x16x32_bf16(af2[i], bfr[j], acc[i][j], 0, 0, 0);
            }
        }

        #pragma unroll
        for (int i = 0; i < 2; i++) {
            #pragma unroll
            for (int rg = 0; rg < 4; rg++) {
                int m = m0 + wm * 32 + i * 16 + quad * 4 + rg;
                #pragma unroll
                for (int j = 0; j < 2; j++) {
                    int n = n0 + wn * 32 + j * 16 + lane15;
                    st_wt32(&out[(size_t)m * DM + n],
                            __float_as_uint(acc[i][j][rg] + bo[n]));
                }
            }
        }
    }
}

// ---------------------------------------------------------------------------
extern "C" void kernel_launch(void* const* d_in, const int* in_sizes, int n_in,
                              void* d_out, int out_size, void* d_ws, size_t ws_size,
                              hipStream_t stream)
{
    const float* x   = (const float*)d_in[0];
    const float* Wqk = (const float*)d_in[1];
    const float* bqk = (const float*)d_in[2];
    const float* Wv  = (const float*)d_in[3];
    const float* bv  = (const float*)d_in[4];
    const float* Wo  = (const float*)d_in[5];
    const float* bo  = (const float*)d_in[6];
    float* out = (float*)d_out;

    const size_t NTOK = (size_t)B_N * S_N * DM;   // 2,097,152
    unsigned int* barmem = (unsigned int*)d_ws;   // 3 barriers x 32KB stride
    float* Asum = (float*)d_ws + 24576;           // past barrier region (96KB)
    float* zsum = Asum + NTOK;                    // 32768 fp32
    unsigned short* xb   = (unsigned short*)(zsum + 32768);
    unsigned short* Wqkb = xb   + NTOK;
    unsigned short* Wvb  = Wqkb + 524288;
    unsigned short* Wob  = Wvb  + 262144;
    unsigned short* qb   = Wob  + 262144;
    unsigned short* kb_  = qb   + NTOK;
    unsigned short* vtb  = kb_  + NTOK;
    unsigned short* ctxb = vtb  + NTOK;

    hipMemsetAsync(barmem, 0, 98304, stream);
    fused_all<<<dim3(NBLK), dim3(256), 0, stream>>>(
        x, Wqk, bqk, Wv, bv, Wo, bo, out, barmem,
        Asum, zsum, xb, Wqkb, Wvb, Wob, qb, kb_, vtb, ctxb);
}